// Round 1
// baseline (106.794 us; speedup 1.0000x reference)
//
#include <hip/hip_runtime.h>
#include <math.h>

namespace {
constexpr int kB = 524288;
constexpr int kC = 128;
constexpr int kBlocks = 2048;
constexpr int kThreads = 256;
constexpr int kWavesPerBlock = kThreads / 64;

struct Partial {
  float sum;     // sum of t = y*log(x) over this block's rows (un-negated)
  float maxv;    // max of per-row loss (-row_sum)
  int   maxidx;  // first index attaining maxv
  int   pad;
};
}  // namespace

__global__ __launch_bounds__(kThreads) void nll_stage1(
    const float* __restrict__ x, const float* __restrict__ y,
    Partial* __restrict__ part) {
  const int tid = threadIdx.x;
  const int waveInBlock = tid >> 6;
  const int half = (tid >> 5) & 1;      // which 32-lane half of the wave
  const int lane32 = tid & 31;          // lane within the half
  const int globalWave = blockIdx.x * kWavesPerBlock + waveInBlock;
  const int rowStride = gridDim.x * kWavesPerBlock * 2;  // 2 rows per wave/iter

  float lsum = 0.0f;              // thread-local sum of t
  float bestv = -INFINITY;        // running row-loss max
  int bestidx = 0x7fffffff;

  for (int row = globalWave * 2 + half; row < kB; row += rowStride) {
    // 32 lanes x float4 = 128 elems = one full row, perfectly coalesced.
    const float4 xv =
        *reinterpret_cast<const float4*>(x + (size_t)row * kC + lane32 * 4);
    const float4 yv =
        *reinterpret_cast<const float4*>(y + (size_t)row * kC + lane32 * 4);
    float t0 = yv.x * __logf(xv.x);
    float t1 = yv.y * __logf(xv.y);
    float t2 = yv.z * __logf(xv.z);
    float t3 = yv.w * __logf(xv.w);
    // nansum semantics: NaN terms count as 0
    t0 = (t0 == t0) ? t0 : 0.0f;
    t1 = (t1 == t1) ? t1 : 0.0f;
    t2 = (t2 == t2) ? t2 : 0.0f;
    t3 = (t3 == t3) ? t3 : 0.0f;
    const float p = (t0 + t1) + (t2 + t3);
    lsum += p;

    // reduce p across the 32 lanes of this half (masks 1..16 stay in-half)
    float r = p;
#pragma unroll
    for (int m = 1; m <= 16; m <<= 1) r += __shfl_xor(r, m, 64);
    const float rowv = -r;
    // rows strictly increase per lane -> strict '>' keeps first max
    if (rowv > bestv) {
      bestv = rowv;
      bestidx = row;
    }
  }

  // wave-level reduce (64 lanes)
#pragma unroll
  for (int m = 1; m <= 32; m <<= 1) {
    lsum += __shfl_xor(lsum, m, 64);
    const float ov = __shfl_xor(bestv, m, 64);
    const int oi = __shfl_xor(bestidx, m, 64);
    if (ov > bestv || (ov == bestv && oi < bestidx)) {
      bestv = ov;
      bestidx = oi;
    }
  }

  __shared__ float s_sum[kWavesPerBlock];
  __shared__ float s_max[kWavesPerBlock];
  __shared__ int s_idx[kWavesPerBlock];
  if ((tid & 63) == 0) {
    s_sum[waveInBlock] = lsum;
    s_max[waveInBlock] = bestv;
    s_idx[waveInBlock] = bestidx;
  }
  __syncthreads();
  if (tid == 0) {
    float bs = 0.0f;
    float bm = -INFINITY;
    int bi = 0x7fffffff;
#pragma unroll
    for (int w = 0; w < kWavesPerBlock; ++w) {
      bs += s_sum[w];
      if (s_max[w] > bm || (s_max[w] == bm && s_idx[w] < bi)) {
        bm = s_max[w];
        bi = s_idx[w];
      }
    }
    part[blockIdx.x].sum = bs;
    part[blockIdx.x].maxv = bm;
    part[blockIdx.x].maxidx = bi;
    part[blockIdx.x].pad = 0;
  }
}

__global__ __launch_bounds__(64) void nll_stage2(
    const Partial* __restrict__ part, float* __restrict__ out) {
  const int lane = threadIdx.x;  // single wave
  double s = 0.0;
  float bm = -INFINITY;
  int bi = 0x7fffffff;
  for (int i = lane; i < kBlocks; i += 64) {
    const Partial p = part[i];
    s += (double)p.sum;
    if (p.maxv > bm || (p.maxv == bm && p.maxidx < bi)) {
      bm = p.maxv;
      bi = p.maxidx;
    }
  }
#pragma unroll
  for (int m = 1; m <= 32; m <<= 1) {
    s += __shfl_xor(s, m, 64);
    const float ov = __shfl_xor(bm, m, 64);
    const int oi = __shfl_xor(bi, m, 64);
    if (ov > bm || (ov == bm && oi < bi)) {
      bm = ov;
      bi = oi;
    }
  }
  if (lane == 0) {
    out[0] = (float)(-s / (double)kB);  // mean of per-row loss
    out[1] = bm;                        // max loss
    out[2] = (float)bi;                 // first argmax index
  }
}

extern "C" void kernel_launch(void* const* d_in, const int* in_sizes, int n_in,
                              void* d_out, int out_size, void* d_ws,
                              size_t ws_size, hipStream_t stream) {
  (void)in_sizes;
  (void)n_in;
  (void)out_size;
  (void)ws_size;
  const float* x = (const float*)d_in[0];
  const float* y = (const float*)d_in[1];
  float* out = (float*)d_out;
  Partial* part = (Partial*)d_ws;

  nll_stage1<<<kBlocks, kThreads, 0, stream>>>(x, y, part);
  nll_stage2<<<1, 64, 0, stream>>>(part, out);
}